// Round 1
// baseline (111.756 us; speedup 1.0000x reference)
//
#include <hip/hip_runtime.h>

// CriticGCN: out = D^-1/2 (A+I) D^-1/2 (x W1) + b1, then @ W_head + b_head.
// Head is linear -> fold W_head through the aggregation:
//   w = W1 @ W_head (100 floats), c = b1.W_head + b_head
//   score[i] = x[i].w ; u[i] = score[i] * rsqrt(deg[i])
//   out[d] = rsqrt(deg[d]) * (sum_{edges s->d} u[s] + u[d]) + c
// Traffic: ~25 MB instead of ~2 GB for the materialized 1024-wide pipeline.

#define N_NODES 50000
#define F_IN    100
#define H_DIM   1024
#define N_EDGES 200000

// Blocks 0..99: w[f] = dot(W1[f,:], W_head). Block 100: c = dot(b1,W_head)+b_head.
// Blocks 101+: grid-stride init deg=1.0 (self loop) and out=0.0 (atomics target).
__global__ void k_init(const float* __restrict__ W1, const float* __restrict__ b1,
                       const float* __restrict__ Wh, const float* __restrict__ bh,
                       float* __restrict__ w, float* __restrict__ c,
                       float* __restrict__ deg, float* __restrict__ out)
{
    const int b = blockIdx.x;
    const int t = threadIdx.x;            // 256 threads
    if (b <= 100) {
        const float* row = (b < 100) ? (W1 + (size_t)b * H_DIM) : b1;
        float s = 0.0f;
        for (int h = t; h < H_DIM; h += 256) s += row[h] * Wh[h];
        #pragma unroll
        for (int off = 32; off > 0; off >>= 1) s += __shfl_down(s, off, 64);
        __shared__ float red[4];
        const int wave = t >> 6, lane = t & 63;
        if (lane == 0) red[wave] = s;
        __syncthreads();
        if (t == 0) {
            float tot = red[0] + red[1] + red[2] + red[3];
            if (b < 100) w[b] = tot;
            else         *c  = tot + bh[0];
        }
    } else {
        const int idx    = (b - 101) * 256 + t;
        const int stride = (gridDim.x - 101) * 256;
        for (int i = idx; i < N_NODES; i += stride) {
            deg[i] = 1.0f;   // self loop
            out[i] = 0.0f;   // accumulation target
        }
    }
}

// deg[dst] += 1 per edge (fp32 exact for counts << 2^24).
__global__ void k_deg(const int* __restrict__ dst, float* __restrict__ deg)
{
    const int e = blockIdx.x * blockDim.x + threadIdx.x;
    if (e < N_EDGES) atomicAdd(&deg[dst[e]], 1.0f);
}

// One wave (64 lanes) per node: u[i] = (x[i].w) * rsqrt(deg[i]).
__global__ void k_score(const float* __restrict__ x, const float* __restrict__ w,
                        const float* __restrict__ deg, float* __restrict__ u)
{
    const int gwave = (blockIdx.x * blockDim.x + threadIdx.x) >> 6;
    const int lane  = threadIdx.x & 63;
    if (gwave >= N_NODES) return;
    const float* row = x + (size_t)gwave * F_IN;
    float s = row[lane] * w[lane];                        // elems 0..63
    if (lane < F_IN - 64) s += row[64 + lane] * w[64 + lane]; // elems 64..99
    #pragma unroll
    for (int off = 32; off > 0; off >>= 1) s += __shfl_down(s, off, 64);
    if (lane == 0) u[gwave] = s * rsqrtf(deg[gwave]);
}

// out[dst] += u[src] per edge (dinv[dst] factored out -> applied in finalize).
__global__ void k_scatter(const int* __restrict__ src, const int* __restrict__ dst,
                          const float* __restrict__ u, float* __restrict__ out)
{
    const int e = blockIdx.x * blockDim.x + threadIdx.x;
    if (e < N_EDGES) atomicAdd(&out[dst[e]], u[src[e]]);
}

// out[i] = rsqrt(deg[i]) * (edge_sum + u[i]) + c
__global__ void k_final(const float* __restrict__ deg, const float* __restrict__ u,
                        const float* __restrict__ c, float* __restrict__ out)
{
    const int i = blockIdx.x * blockDim.x + threadIdx.x;
    if (i < N_NODES) out[i] = rsqrtf(deg[i]) * (out[i] + u[i]) + c[0];
}

extern "C" void kernel_launch(void* const* d_in, const int* in_sizes, int n_in,
                              void* d_out, int out_size, void* d_ws, size_t ws_size,
                              hipStream_t stream)
{
    const float* x   = (const float*)d_in[0];   // (50000,100)
    const int*   ei  = (const int*)  d_in[1];   // (2,200000): src = ei, dst = ei+200000
    const float* W1  = (const float*)d_in[2];   // (100,1024)
    const float* b1  = (const float*)d_in[3];   // (1024,)
    const float* Wh  = (const float*)d_in[4];   // (1024,)
    const float* bh  = (const float*)d_in[5];   // (1,)
    float*       out = (float*)d_out;           // (50000,)

    const int* src = ei;
    const int* dst = ei + N_EDGES;

    // Workspace layout (floats): w[100] | c[1] | pad | deg[50000] | u[50000]
    float* ws_f = (float*)d_ws;
    float* w    = ws_f;
    float* c    = ws_f + 100;
    float* deg  = ws_f + 128;
    float* u    = ws_f + 128 + N_NODES;

    // A: weights fold + init
    k_init<<<101 + 98, 256, 0, stream>>>(W1, b1, Wh, bh, w, c, deg, out);
    // B: degree scatter
    k_deg<<<(N_EDGES + 255) / 256, 256, 0, stream>>>(dst, deg);
    // C: per-node score (wave per node, 4 waves/block)
    k_score<<<(N_NODES + 3) / 4, 256, 0, stream>>>(x, w, deg, u);
    // D: edge scatter of u[src] into out[dst]
    k_scatter<<<(N_EDGES + 255) / 256, 256, 0, stream>>>(src, dst, u, out);
    // E: finalize
    k_final<<<(N_NODES + 255) / 256, 256, 0, stream>>>(deg, u, c, out);
}

// Round 2
// 108.752 us; speedup vs baseline: 1.0276x; 1.0276x over previous
//
#include <hip/hip_runtime.h>

// CriticGCN: out = D^-1/2 (A+I) D^-1/2 (x W1) + b1, then @ W_head + b_head.
// Head is linear -> fold W_head through the aggregation:
//   w = W1 @ W_head (100 floats), c = b1.W_head + b_head
//   score s[i] = x[i].w ; u[i] = s[i] * dinv[i],  dinv[i] = rsqrt(deg[i]+1)
//   out[d] = dinv[d] * (sum_{edges s->d} u[s] + u[d]) + c
//
// R2: native atomics. Plain fp32 atomicAdd compiles to a CAS loop on AMD
// (no -munsafe-fp-atomics); with ~5-way collisions over 250k edge atomics
// that dominated R1's 112 us. deg now uses native u32 atomics; the edge
// scatter uses unsafeAtomicAdd (native global_atomic_add_f32). deg-scatter
// fused with the weight-fold kernel; zero-init via one hipMemsetAsync.

#define N_NODES 50000
#define F_IN    100
#define H_DIM   1024
#define N_EDGES 200000

// Blocks 0..99: w[f] = dot(W1[f,:], W_head). Block 100: c = dot(b1,W_head)+bh.
// Blocks 101+: one thread per edge, deg[dst] += 1 (native u32 atomic).
// Independent halves -> safe to fuse (nothing here reads deg or w).
__global__ void k_fold_deg(const float* __restrict__ W1, const float* __restrict__ b1,
                           const float* __restrict__ Wh, const float* __restrict__ bh,
                           const int* __restrict__ dst,
                           float* __restrict__ w, float* __restrict__ c,
                           unsigned* __restrict__ deg)
{
    const int b = blockIdx.x;
    const int t = threadIdx.x;            // 256 threads
    if (b <= 100) {
        const float* row = (b < 100) ? (W1 + (size_t)b * H_DIM) : b1;
        float s = 0.0f;
        for (int h = t; h < H_DIM; h += 256) s += row[h] * Wh[h];
        #pragma unroll
        for (int off = 32; off > 0; off >>= 1) s += __shfl_down(s, off, 64);
        __shared__ float red[4];
        const int wave = t >> 6, lane = t & 63;
        if (lane == 0) red[wave] = s;
        __syncthreads();
        if (t == 0) {
            float tot = red[0] + red[1] + red[2] + red[3];
            if (b < 100) w[b] = tot;
            else         *c  = tot + bh[0];
        }
    } else {
        const int e = (b - 101) * 256 + t;
        if (e < N_EDGES) atomicAdd(&deg[dst[e]], 1u);
    }
}

// One wave per node: u[i] = (x[i].w) * rsqrt(deg[i]+1). Lane j loads x[i*100+j]
// (coalesced); two strips cover F_IN=100.
__global__ void k_score(const float* __restrict__ x, const float* __restrict__ w,
                        const unsigned* __restrict__ deg, float* __restrict__ u)
{
    const int gwave = (blockIdx.x * blockDim.x + threadIdx.x) >> 6;
    const int lane  = threadIdx.x & 63;
    if (gwave >= N_NODES) return;
    const float* row = x + (size_t)gwave * F_IN;
    float s = row[lane] * w[lane];                             // elems 0..63
    if (lane < F_IN - 64) s += row[64 + lane] * w[64 + lane];  // elems 64..99
    #pragma unroll
    for (int off = 32; off > 0; off >>= 1) s += __shfl_down(s, off, 64);
    if (lane == 0) u[gwave] = s * rsqrtf((float)deg[gwave] + 1.0f);
}

// acc[dst] += u[src] per edge — native fp32 atomic (no CAS loop).
__global__ void k_scatter(const int* __restrict__ src, const int* __restrict__ dst,
                          const float* __restrict__ u, float* __restrict__ acc)
{
    const int e = blockIdx.x * blockDim.x + threadIdx.x;
    if (e < N_EDGES) unsafeAtomicAdd(&acc[dst[e]], u[src[e]]);
}

// out[i] = rsqrt(deg[i]+1) * (acc[i] + u[i]) + c
__global__ void k_final(const unsigned* __restrict__ deg, const float* __restrict__ u,
                        const float* __restrict__ acc, const float* __restrict__ c,
                        float* __restrict__ out)
{
    const int i = blockIdx.x * blockDim.x + threadIdx.x;
    if (i < N_NODES)
        out[i] = rsqrtf((float)deg[i] + 1.0f) * (acc[i] + u[i]) + c[0];
}

extern "C" void kernel_launch(void* const* d_in, const int* in_sizes, int n_in,
                              void* d_out, int out_size, void* d_ws, size_t ws_size,
                              hipStream_t stream)
{
    const float* x   = (const float*)d_in[0];   // (50000,100)
    const int*   ei  = (const int*)  d_in[1];   // (2,200000)
    const float* W1  = (const float*)d_in[2];   // (100,1024)
    const float* b1  = (const float*)d_in[3];   // (1024,)
    const float* Wh  = (const float*)d_in[4];   // (1024,)
    const float* bh  = (const float*)d_in[5];   // (1,)
    float*       out = (float*)d_out;           // (50000,)

    const int* src = ei;
    const int* dst = ei + N_EDGES;

    // ws layout (4B units): w[100] c[1] pad->128 | deg[50000] | acc[50000] | u[50000]
    float*    ws_f = (float*)d_ws;
    float*    w    = ws_f;
    float*    c    = ws_f + 100;
    unsigned* deg  = (unsigned*)(ws_f + 128);
    float*    acc  = ws_f + 128 + N_NODES;
    float*    u    = ws_f + 128 + 2 * N_NODES;

    // Zero deg + acc in one shot (contiguous, 400 KB). Graph-capture safe.
    hipMemsetAsync(deg, 0, 2 * N_NODES * sizeof(float), stream);

    // A: weight fold (blocks 0..100) + degree scatter (blocks 101+)
    k_fold_deg<<<101 + (N_EDGES + 255) / 256, 256, 0, stream>>>(
        W1, b1, Wh, bh, dst, w, c, deg);
    // B: per-node score (wave per node, 4 waves/block)
    k_score<<<(N_NODES + 3) / 4, 256, 0, stream>>>(x, w, deg, u);
    // C: edge scatter of u[src] into acc[dst] (native fp atomic)
    k_scatter<<<(N_EDGES + 255) / 256, 256, 0, stream>>>(src, dst, u, acc);
    // D: finalize
    k_final<<<(N_NODES + 255) / 256, 256, 0, stream>>>(deg, u, acc, c, out);
}